// Round 17
// baseline (203.602 us; speedup 1.0000x reference)
//
#include <hip/hip_runtime.h>
#include <cstddef>
#include <cstdint>

#define B_SZ 8
#define T_SEQ 1024
#define D_MODEL 1024
#define NH 16
#define HD 64
#define TE_DIM 2048
#define BT_ROWS 8192

typedef short bf16x8 __attribute__((ext_vector_type(8)));
typedef float f32x4 __attribute__((ext_vector_type(4)));

#define MFMA16(a, b, c) __builtin_amdgcn_mfma_f32_16x16x32_bf16(a, b, c, 0, 0, 0)
#define EXP2(x) __builtin_amdgcn_exp2f(x)

__device__ inline unsigned short f2b(float f) {
  union { float f; unsigned u; } v; v.f = f;
  unsigned r = v.u + 0x7FFF + ((v.u >> 16) & 1);
  return (unsigned short)(r >> 16);
}

__device__ inline float b2f(unsigned short u) {
  union { unsigned u; float f; } v; v.u = ((unsigned)u) << 16; return v.f;
}

__device__ inline unsigned cvtpk(float a, float b) {
  unsigned r;
  asm("v_cvt_pk_bf16_f32 %0, %1, %2" : "=v"(r) : "v"(a), "v"(b));
  return r;
}

__device__ inline float max3f(float a, float b, float c) {
  return fmaxf(fmaxf(a, b), c);
}

__device__ inline void gll16(const void* g, void* l) {
  __builtin_amdgcn_global_load_lds(
      (const __attribute__((address_space(1))) unsigned int*)g,
      (__attribute__((address_space(3))) unsigned int*)l, 16, 0, 0);
}

// --- prep: ln (0..8191) + transposes (8192..12287) + emb_partial (12288..12415)
__global__ __launch_bounds__(256) void prep_kernel(
    const float* __restrict__ x, const float* __restrict__ norm_w,
    const float* __restrict__ norm_b, unsigned short* __restrict__ xn,
    const float* __restrict__ s0, const float* __restrict__ s1,
    const float* __restrict__ s2, const float* __restrict__ s3,
    unsigned short* __restrict__ d0, unsigned short* __restrict__ d1,
    unsigned short* __restrict__ d2, unsigned short* __restrict__ d3,
    const float* __restrict__ emb, const float* __restrict__ emb_w,
    float* __restrict__ partial)
{
  __shared__ float red[8];
  __shared__ float sT[32][33];
  __shared__ float ses[B_SZ][32];
  int bid = blockIdx.x;
  int tid = threadIdx.x;
  if (bid < BT_ROWS) {
    // ---------------- LayerNorm (bf16, chunk-swizzled out) ----------------
    int row = bid;
    const float* xr = x + (size_t)row * D_MODEL;
    float4 xv = *(const float4*)&xr[tid * 4];
    float s  = xv.x + xv.y + xv.z + xv.w;
    float ss = xv.x*xv.x + xv.y*xv.y + xv.z*xv.z + xv.w*xv.w;
    #pragma unroll
    for (int off = 32; off; off >>= 1) {
      s  += __shfl_xor(s, off);
      ss += __shfl_xor(ss, off);
    }
    int wv = tid >> 6;
    if ((tid & 63) == 0) { red[wv] = s; red[4 + wv] = ss; }
    __syncthreads();
    s  = red[0] + red[1] + red[2] + red[3];
    ss = red[4] + red[5] + red[6] + red[7];
    float mean = s * (1.f / D_MODEL);
    float var  = ss * (1.f / D_MODEL) - mean * mean;
    float inv  = rsqrtf(var + 1e-5f);
    float4 w4 = *(const float4*)&norm_w[tid * 4];
    float4 b4 = *(const float4*)&norm_b[tid * 4];
    ushort4 o;
    o.x = f2b((xv.x - mean) * inv * w4.x + b4.x);
    o.y = f2b((xv.y - mean) * inv * w4.y + b4.y);
    o.z = f2b((xv.z - mean) * inv * w4.z + b4.z);
    o.w = f2b((xv.w - mean) * inv * w4.w + b4.w);
    int kg = tid >> 4, cb = (tid >> 1) & 7, e = (tid & 1) * 4;
    int col = kg * 64 + ((cb ^ (row & 7)) * 8) + e;
    *(ushort4*)&xn[(size_t)row * D_MODEL + col] = o;
  } else if (bid < BT_ROWS + 4096) {
    // ------- weight transpose fp32 [K][N] -> bf16 [N][K] swizzled -------
    int tb = bid - BT_ROWS;
    int z = tb >> 10, yy = (tb >> 5) & 31, xx = tb & 31;
    const float* in = z == 0 ? s0 : z == 1 ? s1 : z == 2 ? s2 : s3;
    unsigned short* out = z == 0 ? d0 : z == 1 ? d1 : z == 2 ? d2 : d3;
    int tx = tid & 31, ty = tid >> 5;
    int r0 = yy * 32, c0 = xx * 32;
    #pragma unroll
    for (int rr = 0; rr < 4; ++rr)
      sT[ty + rr * 8][tx] = in[(size_t)(r0 + ty + rr * 8) * D_MODEL + c0 + tx];
    __syncthreads();
    int k = r0 + tx;
    int kg = k >> 6, cb = (k >> 3) & 7, e = k & 7;
    #pragma unroll
    for (int rr = 0; rr < 4; ++rr) {
      int n = c0 + ty + rr * 8;
      int col = kg * 64 + ((cb ^ (n & 7)) * 8) + e;
      out[(size_t)n * D_MODEL + col] = f2b(sT[tx][ty + rr * 8]);
    }
  } else {
    // ---------------- emb split-K partial ----------------
    int tb2 = bid - (BT_ROWS + 4096);   // 0..127
    int colb = tb2 & 1, kb = tb2 >> 1;
    int t0 = kb * 32;
    {
      int b = tid >> 5, t = tid & 31;
      float v = emb[b * TE_DIM + t0 + t];
      ses[b][t] = v / (1.f + __expf(-v));
    }
    __syncthreads();
    int n = colb * 1024 + tid * 4;
    f32x4 acc[B_SZ];
    #pragma unroll
    for (int b = 0; b < B_SZ; ++b) acc[b] = (f32x4){0.f, 0.f, 0.f, 0.f};
    #pragma unroll 4
    for (int t = 0; t < 32; ++t) {
      f32x4 wv = *(const f32x4*)&emb_w[(size_t)(t0 + t) * (2 * D_MODEL) + n];
      #pragma unroll
      for (int b = 0; b < B_SZ; ++b) {
        float s = ses[b][t];
        acc[b][0] = fmaf(s, wv[0], acc[b][0]);
        acc[b][1] = fmaf(s, wv[1], acc[b][1]);
        acc[b][2] = fmaf(s, wv[2], acc[b][2]);
        acc[b][3] = fmaf(s, wv[3], acc[b][3]);
      }
    }
    #pragma unroll
    for (int b = 0; b < B_SZ; ++b)
      *(f32x4*)&partial[((size_t)kb * B_SZ + b) * (2 * D_MODEL) + n] = acc[b];
  }
}

// ------------- pipelined 256x128 QKV GEMM, 3-slot LDS ring (66us) -----------
__global__ __launch_bounds__(512, 2) void gemm_qkv8(
    const unsigned short* __restrict__ A, const unsigned short* __restrict__ W,
    const float* __restrict__ b0, const float* __restrict__ b1,
    const float* __restrict__ b2, const float* __restrict__ mask,
    unsigned short* __restrict__ O)
{
  const int K = 1024;
  __shared__ __align__(16) unsigned short SA[3][256 * 64];  // 96 KB
  __shared__ __align__(16) unsigned short SB[3][128 * 64];  // 48 KB
  int tid = threadIdx.x;
  int wid = tid >> 6, lane = tid & 63, g = lane >> 4, lq = lane & 15;
  int wm = wid >> 1, wn = wid & 1;
  int bid = blockIdx.x;
  int xcd = bid & 7, ii = bid >> 3;
  int mt = xcd * 4 + (ii & 3), nt = ii >> 2;
  int m0 = mt * 256;
  int wg = nt >> 3;
  int n0 = (nt & 7) * 128;
  const unsigned short* Bt = W + ((size_t)wg << 20);
  const float* bias = wg == 0 ? b0 : wg == 1 ? b1 : b2;

  f32x4 acc[4][4];
  #pragma unroll
  for (int i = 0; i < 4; ++i)
    #pragma unroll
    for (int j = 0; j < 4; ++j)
      acc[i][j] = (f32x4){0.f, 0.f, 0.f, 0.f};

  const unsigned short* aSrc = A + (size_t)(m0 + (tid >> 3)) * K + (tid & 7) * 8;
  const unsigned short* bSrc = Bt + (size_t)(n0 + (tid >> 3)) * K + (tid & 7) * 8;

  #define STAGE8(slot, t)                                                      \
    {                                                                          \
      size_t ko = (size_t)(t) * 64;                                            \
      _Pragma("unroll")                                                        \
      for (int i2 = 0; i2 < 4; ++i2)                                           \
        gll16(aSrc + ko + (size_t)i2 * 64 * K,                                 \
              (char*)&SA[slot][0] + tid * 16 + i2 * 8192);                     \
      _Pragma("unroll")                                                        \
      for (int i2 = 0; i2 < 2; ++i2)                                           \
        gll16(bSrc + ko + (size_t)i2 * 64 * K,                                 \
              (char*)&SB[slot][0] + tid * 16 + i2 * 8192);                     \
    }

  STAGE8(0, 0)
  STAGE8(1, 1)
  asm volatile("s_waitcnt vmcnt(6)" ::: "memory");
  asm volatile("s_barrier" ::: "memory");

  int cA0 = (g ^ (lq & 7)) * 16;
  int cA1 = ((4 + g) ^ (lq & 7)) * 16;

  #pragma unroll
  for (int t = 0; t < 16; ++t) {
    const char* sa = (const char*)&SA[t % 3][0];
    const char* sb = (const char*)&SB[t % 3][0];
    bf16x8 af[4][2], bf[4][2];
    #pragma unroll
    for (int i = 0; i < 4; ++i) {
      int ra = wm * 64 + i * 16 + lq;
      af[i][0] = *(const bf16x8*)(sa + ra * 128 + cA0);
      af[i][1] = *(const bf16x8*)(sa + ra * 128 + cA1);
      int rb = wn * 64 + i * 16 + lq;
      bf[i][0] = *(const bf16x8*)(sb + rb * 128 + cA0);
      bf[i][1] = *(const bf16x8*)(sb + rb * 128 + cA1);
    }
    if (t < 14) {
      STAGE8((t + 2) % 3, t + 2)
      asm volatile("s_waitcnt vmcnt(6)" ::: "memory");
    } else if (t == 14) {
      asm volatile("s_waitcnt vmcnt(0)" ::: "memory");
    }
    __builtin_amdgcn_s_setprio(1);
    #pragma unroll
    for (int i = 0; i < 4; ++i)
      #pragma unroll
      for (int j = 0; j < 4; ++j) {
        acc[i][j] = MFMA16(af[i][0], bf[j][0], acc[i][j]);
        acc[i][j] = MFMA16(af[i][1], bf[j][1], acc[i][j]);
      }
    __builtin_amdgcn_s_setprio(0);
    if (t < 15) asm volatile("s_barrier" ::: "memory");
  }
  #undef STAGE8

  int colbase = n0 + wn * 64;
  #pragma unroll
  for (int i = 0; i < 4; ++i) {
    int mrow0 = m0 + wm * 64 + i * 16 + g * 4;
    #pragma unroll
    for (int j = 0; j < 4; ++j) {
      int n = colbase + j * 16 + lq;
      float bv = bias[n];
      int h = n >> 6, dd = n & 63;
      if (wg < 2) {
        float scale = wg == 0 ? 1.44269504f : 1.0f;  // Q pre-scaled for exp2
        unsigned short* Cb = O + ((size_t)wg << 23);
        #pragma unroll
        for (int rr = 0; rr < 4; ++rr) {
          int m = mrow0 + rr;
          int b = m >> 10, tt = m & 1023;
          Cb[((size_t)((b * NH + h) * T_SEQ + tt)) * HD + dd] = f2b((acc[i][j][rr] + bv) * scale);
        }
      } else {
        unsigned short* Cb = O + ((size_t)2 << 23);
        int b = mrow0 >> 10, tt = mrow0 & 1023;
        ushort4 pk;
        unsigned short* pp = (unsigned short*)&pk;
        #pragma unroll
        for (int rr = 0; rr < 4; ++rr)
          pp[rr] = f2b((acc[i][j][rr] + bv) * mask[mrow0 + rr]);
        *(ushort4*)&Cb[((size_t)((b * NH + h) * HD + dd)) * T_SEQ + tt] = pk;
      }
    }
  }
}

// ---------------- out GEMM (proven 128x128 / 4-wave, ~24us) --------
__global__ __launch_bounds__(256) void gemm_out(
    const unsigned short* __restrict__ A, const unsigned short* __restrict__ Bt,
    const float* __restrict__ bias, const float* __restrict__ resid,
    float* __restrict__ C)
{
  const int K = 1024;
  __shared__ __align__(16) unsigned short As[128 * 64];
  __shared__ __align__(16) unsigned short Bs[128 * 64];
  int l = blockIdx.x;
  int xcd = l & 7, ii = l >> 3;
  int mt = xcd * 8 + (ii & 7), nt = ii >> 3;
  int m0 = mt * 128, n0 = nt * 128;

  int tid = threadIdx.x;
  int lane = tid & 63, w = tid >> 6;
  int g = lane >> 4, lq = lane & 15;
  int wr = w >> 1, wc = w & 1;
  f32x4 acc[4][4];
  #pragma unroll
  for (int i = 0; i < 4; ++i)
    #pragma unroll
    for (int j = 0; j < 4; ++j)
      acc[i][j] = (f32x4){0.f, 0.f, 0.f, 0.f};

  const unsigned short* aSrc = A + (size_t)(m0 + (tid >> 3)) * K + (tid & 7) * 8;
  const unsigned short* bSrc = Bt + (size_t)(n0 + (tid >> 3)) * K + (tid & 7) * 8;
  char* aDst = (char*)As + tid * 16;
  char* bDst = (char*)Bs + tid * 16;

  for (int k0 = 0; k0 < K; k0 += 64) {
    #pragma unroll
    for (int it = 0; it < 4; ++it) {
      gll16(aSrc + k0 + it * 32 * K, aDst + it * 4096);
      gll16(bSrc + k0 + it * 32 * K, bDst + it * 4096);
    }
    __syncthreads();
    #pragma unroll
    for (int kh = 0; kh < 2; ++kh) {
      bf16x8 af[4], bfr[4];
      #pragma unroll
      for (int i = 0; i < 4; ++i) {
        int ra = wr * 64 + i * 16 + lq;
        af[i] = *(const bf16x8*)((const char*)As + ra * 128 + (((kh * 4 + g) ^ (ra & 7)) * 16));
        int rb = wc * 64 + i * 16 + lq;
        bfr[i] = *(const bf16x8*)((const char*)Bs + rb * 128 + (((kh * 4 + g) ^ (rb & 7)) * 16));
      }
      #pragma unroll
      for (int i = 0; i < 4; ++i)
        #pragma unroll
        for (int j = 0; j < 4; ++j)
          acc[i][j] = MFMA16(af[i], bfr[j], acc[i][j]);
    }
    __syncthreads();
  }

  int colbase = n0 + wc * 64;
  #pragma unroll
  for (int i = 0; i < 4; ++i) {
    int mrow0 = m0 + wr * 64 + i * 16 + g * 4;
    #pragma unroll
    for (int j = 0; j < 4; ++j) {
      int n = colbase + j * 16 + lq;
      float bv = bias[n];
      #pragma unroll
      for (int rr = 0; rr < 4; ++rr) {
        int m = mrow0 + rr;
        C[(size_t)m * D_MODEL + n] = acc[i][j][rr] + bv + resid[(size_t)m * D_MODEL + n];
      }
    }
  }
}

// --- MFMA flash attention v8: 8 waves/block, 32q/wave (qa=2), 256q/block ----
// blocks 0..511 attn; 512..543 emb_reduce. LDS 64KB -> 2 blocks/CU,
// 16 waves/CU (4/SIMD) to hide the QK->softmax->PV dependency chain.
__global__ __launch_bounds__(512, 2) void attn_mfma8(
    const unsigned short* __restrict__ Q, const unsigned short* __restrict__ K,
    const unsigned short* __restrict__ Vt, const float* __restrict__ mask,
    unsigned short* __restrict__ y,
    const float* __restrict__ partial, const float* __restrict__ emb_b,
    float* __restrict__ e)
{
  __shared__ __align__(16) unsigned short SM[32768];   // 64 KB total
  int tid = threadIdx.x;
  int bid = blockIdx.x;

  if (bid >= 512) {
    // ---------------- emb_reduce (512 threads) ----------------
    int idx = (bid - 512) * 512 + tid;
    int b = idx >> 11, n = idx & 2047;
    float acc = emb_b[n];
    #pragma unroll 8
    for (int kb = 0; kb < 64; ++kb)
      acc += partial[((size_t)kb * B_SZ + b) * (2 * D_MODEL) + n];
    e[b * (2 * D_MODEL) + n] = acc;
    return;
  }

  unsigned short* Kb = SM;            // [2][4096]
  unsigned short* Vb = SM + 8192;     // [2][4096]
  unsigned short* Pb = SM + 16384;    // [8 waves][2 qa][1024]

  int w = tid >> 6, lane = tid & 63;
  int g = lane >> 4, lq = lane & 15;
  int lid = (bid & 7) * 64 + (bid >> 3);   // XCD remap
  int qb = lid & 3, h = (lid >> 2) & 15, b = lid >> 6;
  int q0 = qb * 256 + w * 32;
  size_t hb = ((size_t)(b * NH + h)) * T_SEQ * HD;

  bf16x8 bq[2][2];
  #pragma unroll
  for (int qa = 0; qa < 2; ++qa)
    #pragma unroll
    for (int kh = 0; kh < 2; ++kh)
      bq[qa][kh] = *(const bf16x8*)(Q + hb + (size_t)(q0 + qa * 16 + lq) * HD + kh * 32 + g * 8);

  bf16x8 ones;
  #pragma unroll
  for (int i = 0; i < 8; ++i) ones[i] = (short)16256;  // bf16 1.0

  // per-wave staging: wave w stages chunk w of K and of V
  const char* kBase = (const char*)(K + hb) + lq * 128 + g * 16;
  const char* vBase = (const char*)(Vt + hb) + lq * 2048 + g * 16;
  const char* kSw = kBase + (w >> 1) * 2048 + (w & 1) * 64;
  const char* vSw = vBase + (w >> 1) * 32768 + (w & 1) * 64;

  f32x4 o[4][2];   // [dt][qa]
  f32x4 osum[2];
  #pragma unroll
  for (int qa = 0; qa < 2; ++qa) {
    osum[qa] = (f32x4){0.f, 0.f, 0.f, 0.f};
    #pragma unroll
    for (int dt = 0; dt < 4; ++dt)
      o[dt][qa] = (f32x4){0.f, 0.f, 0.f, 0.f};
  }
  float mrun[2] = {-3.0e38f, -3.0e38f};
  const float* maskb = mask + b * T_SEQ;

  gll16(kSw, Kb + w * 512);
  gll16(vSw, Vb + w * 512);
  __syncthreads();

  for (int t = 0; t < 16; ++t) {
    int cur = t & 1;
    int kv0 = t * 64;
    if (t < 15) {
      int nxt = cur ^ 1;
      size_t ko = (size_t)(kv0 + 64) * 128;
      size_t vo = (size_t)(kv0 + 64) * 2;
      gll16(kSw + ko, Kb + nxt * 4096 + w * 512);
      gll16(vSw + vo, Vb + nxt * 4096 + w * 512);
    }
    const unsigned short* Kc = Kb + cur * 4096;
    const unsigned short* Vc = Vb + cur * 4096;

    f32x4 mbv[4];
    #pragma unroll
    for (int kt = 0; kt < 4; ++kt) {
      float4 mk = *(const float4*)&maskb[kv0 + kt * 16 + g * 4];
      mbv[kt][0] = fmaf(mk.x, 1500000.f, -1500000.f);
      mbv[kt][1] = fmaf(mk.y, 1500000.f, -1500000.f);
      mbv[kt][2] = fmaf(mk.z, 1500000.f, -1500000.f);
      mbv[kt][3] = fmaf(mk.w, 1500000.f, -1500000.f);
    }

    bf16x8 kf[4][2];
    #pragma unroll
    for (int kt = 0; kt < 4; ++kt)
      #pragma unroll
      for (int kh = 0; kh < 2; ++kh)
        kf[kt][kh] = *(const bf16x8*)(Kc + (kt * 2 + kh) * 512 + lane * 8);

    f32x4 st[4][2];
    __builtin_amdgcn_s_setprio(1);
    #pragma unroll
    for (int kt = 0; kt < 4; ++kt)
      #pragma unroll
      for (int qa = 0; qa < 2; ++qa) {
        st[kt][qa] = MFMA16(kf[kt][0], bq[qa][0], mbv[kt]);   // bias as C-init
        st[kt][qa] = MFMA16(kf[kt][1], bq[qa][1], st[kt][qa]);
      }
    __builtin_amdgcn_s_setprio(0);

    bf16x8 vf[4][2];
    #pragma unroll
    for (int dt = 0; dt < 4; ++dt)
      #pragma unroll
      for (int kh = 0; kh < 2; ++kh)
        vf[dt][kh] = *(const bf16x8*)(Vc + (dt * 2 + kh) * 512 + lane * 8);

    float tmax[2];
    #pragma unroll
    for (int qa = 0; qa < 2; ++qa) {
      float m0v = max3f(st[0][qa][0], st[0][qa][1], st[0][qa][2]);
      float m1v = max3f(st[0][qa][3], st[1][qa][0], st[1][qa][1]);
      float m2v = max3f(st[1][qa][2], st[1][qa][3], st[2][qa][0]);
      float m3v = max3f(st[2][qa][1], st[2][qa][2], st[2][qa][3]);
      float m4v = max3f(st[3][qa][0], st[3][qa][1], st[3][qa][2]);
      float t0v = max3f(m0v, m1v, st[3][qa][3]);
      float t1v = max3f(m2v, m3v, m4v);
      float tm = fmaxf(t0v, t1v);
      tm = fmaxf(tm, __shfl_xor(tm, 16));
      tm = fmaxf(tm, __shfl_xor(tm, 32));
      tmax[qa] = tm;
    }
    bool need = (tmax[0] > mrun[0] + 11.5f) || (tmax[1] > mrun[1] + 11.5f);
    if (__any((int)need)) {
      #pragma unroll
      for (int qa = 0; qa < 2; ++qa) {
        float mnew = fmaxf(mrun[qa], tmax[qa]);
        float corr = EXP2(mrun[qa] - mnew);
        osum[qa][0] *= corr; osum[qa][1] *= corr;
        osum[qa][2] *= corr; osum[qa][3] *= corr;
        #pragma unroll
        for (int dt = 0; dt < 4; ++dt) {
          o[dt][qa][0] *= corr; o[dt][qa][1] *= corr;
          o[dt][qa][2] *= corr; o[dt][qa][3] *= corr;
        }
        mrun[qa] = mnew;
      }
    }
    #pragma unroll
    for (int qa = 0; qa < 2; ++qa)
      #pragma unroll
      for (int kt = 0; kt < 4; ++kt)
        #pragma unroll
        for (int r = 0; r < 4; ++r)
          st[kt][qa][r] = EXP2(st[kt][qa][r] - mrun[qa]);

    #pragma unroll
    for (int qa = 0; qa < 2; ++qa) {
      unsigned short* Pq = Pb + (w * 2 + qa) * 1024;
      #pragma unroll
      for (int kt = 0; kt < 4; ++kt) {
        uint2 pk2;
        pk2.x = cvtpk(st[kt][qa][0], st[kt][qa][1]);
        pk2.y = cvtpk(st[kt][qa][2], st[kt][qa][3]);
        *(uint2*)((char*)Pq + lq * 128 +
                  (((kt * 2 + (g >> 1)) ^ (lq & 7)) * 16) + (g & 1) * 8) = pk2;
      }
    }

    __builtin_amdgcn_s_setprio(1);
    #pragma unroll
    for (int qa = 0; qa < 2; ++qa) {
      const unsigned short* Pq = Pb + (w * 2 + qa) * 1024;
      #pragma unroll
      for (int kh = 0; kh < 2; ++kh) {
        bf16x8 pa = *(const bf16x8*)((const char*)Pq + lq * 128 +
                                     (((kh * 4 + g) ^ (lq & 7)) * 16));
        osum[qa] = MFMA16(ones, pa, osum[qa]);   // l via matrix pipe
        #pragma unroll
        for (int dt = 0; dt < 4; ++dt)
          o[dt][qa] = MFMA16(vf[dt][kh], pa, o[dt][qa]);
      }
    }
    __builtin_amdgcn_s_setprio(0);

    __syncthreads();
  }

  // epilogue: per-wave 32x64 bf16 transpose in SM (K/V region dead)
  unsigned short* sc = SM + w * 2048;
  #pragma unroll
  for (int qa = 0; qa < 2; ++qa) {
    float inv = 1.f / osum[qa][0];
    #pragma unroll
    for (int dt = 0; dt < 4; ++dt) {
      uint2 pk;
      pk.x = cvtpk(o[dt][qa][0] * inv, o[dt][qa][1] * inv);
      pk.y = cvtpk(o[dt][qa][2] * inv, o[dt][qa][3] * inv);
      *(uint2*)(sc + (qa * 16 + lq) * 64 + dt * 16 + g * 4) = pk;
    }
  }
  #pragma unroll
  for (int it = 0; it < 8; ++it) {
    int row = it * 4 + g;
    ushort4 v = *(const ushort4*)(sc + row * 64 + lq * 4);
    *(ushort4*)&y[(size_t)(b * T_SEQ + q0 + row) * D_MODEL + h * HD + lq * 4] = v;
  }
}

// -------- g = silu(LN(y)*(1+scale)+shift)  (bf16 in/out, swizzled out) ------
__global__ __launch_bounds__(256) void ln2_kernel(
    const unsigned short* __restrict__ y, const float* __restrict__ w,
    const float* __restrict__ b, const float* __restrict__ e,
    unsigned short* __restrict__ gout)
{
  __shared__ float red[8];
  int row = blockIdx.x;
  int tid = threadIdx.x;
  int bb = row >> 10;
  ushort4 u = *(const ushort4*)&y[(size_t)row * D_MODEL + tid * 4];
  float4 yv = {b2f(u.x), b2f(u.y), b2f(u.z), b2f(u.w)};
  float s  = yv.x + yv.y + yv.z + yv.w;
  float ss = yv.x*yv.x + yv.y*yv.y + yv.z*yv.z + yv.w*yv.w;
  #pragma unroll
  for (int off = 32; off; off >>= 1) {
    s  += __shfl_xor(s, off);
    ss += __shfl_xor(ss, off);
  }
  int wv = tid >> 6;
  if ((tid & 63) == 0) { red[wv] = s; red[4 + wv] = ss; }
  __syncthreads();
  s  = red[0] + red[1] + red[2] + red[3];
  ss = red[4] + red[5] + red[6] + red[7];
  float mean = s * (1.f / D_MODEL);
  float var  = ss * (1.f / D_MODEL) - mean * mean;
  float inv  = rsqrtf(var + 1e-5f);
  float vals[4] = {yv.x, yv.y, yv.z, yv.w};
  ushort4 o;
  unsigned short* op = (unsigned short*)&o;
  #pragma unroll
  for (int j = 0; j < 4; j++) {
    int c = tid * 4 + j;
    float val = (vals[j] - mean) * inv * w[c] + b[c];
    float sc = e[bb * (2 * D_MODEL) + c];
    float sh = e[bb * (2 * D_MODEL) + D_MODEL + c];
    val = val * (1.f + sc) + sh;
    op[j] = f2b(val / (1.f + __expf(-val)));
  }
  int kg = tid >> 4, cb = (tid >> 1) & 7, ee = (tid & 1) * 4;
  int col = kg * 64 + ((cb ^ (row & 7)) * 8) + ee;
  *(ushort4*)&gout[(size_t)row * D_MODEL + col] = o;
}

extern "C" void kernel_launch(void* const* d_in, const int* in_sizes, int n_in,
                              void* d_out, int out_size, void* d_ws, size_t ws_size,
                              hipStream_t stream) {
  const float* x      = (const float*)d_in[0];
  const float* emb    = (const float*)d_in[1];
  const float* mask   = (const float*)d_in[2];
  const float* norm_w = (const float*)d_in[3];
  const float* norm_b = (const float*)d_in[4];
  const float* q_w    = (const float*)d_in[5];
  const float* q_b    = (const float*)d_in[6];
  const float* k_w    = (const float*)d_in[7];
  const float* k_b    = (const float*)d_in[8];
  const float* v_w    = (const float*)d_in[9];
  const float* v_b    = (const float*)d_in[10];
  const float* emb_w  = (const float*)d_in[11];
  const float* emb_b  = (const float*)d_in[12];
  const float* sb_w   = (const float*)d_in[13];
  const float* sb_b   = (const float*)d_in[14];
  const float* out_w  = (const float*)d_in[15];
  const float* out_b  = (const float*)d_in[16];
  float* out = (float*)d_out;

  char* ws = (char*)d_ws;
  const size_t MB = 1u << 20;
  unsigned short* xn   = (unsigned short*)(ws);             // 16 MB bf16 swz
  unsigned short* qkv  = (unsigned short*)(ws + 16 * MB);   // 48 MB: qb|kb|vt
  unsigned short* qb   = qkv;
  unsigned short* kb   = qkv + (1u << 23);
  unsigned short* vt   = qkv + (2u << 23);
  unsigned short* yb   = (unsigned short*)(ws + 64 * MB);   // 16 MB bf16 y
  unsigned short* gb   = (unsigned short*)(ws + 96 * MB);   // 16 MB bf16 swz
  float*          ep   = (float*)(ws + 96 * MB);            // 4 MB (dead before gb)
  unsigned short* w3t  = (unsigned short*)(ws + 112 * MB);  // 6 MB: qwt|kwt|vwt
  unsigned short* owt  = (unsigned short*)(ws + 118 * MB);  // 2 MB
  float*          eb   = (float*)(ws + 120 * MB);           // 64 KB

  prep_kernel<<<BT_ROWS + 4096 + 128, 256, 0, stream>>>(
      x, norm_w, norm_b, xn,
      q_w, k_w, v_w, out_w,
      w3t, w3t + (1u << 20), w3t + (2u << 20), owt,
      emb, emb_w, ep);

  gemm_qkv8<<<768, 512, 0, stream>>>(xn, w3t, q_b, k_b, v_b, mask, qkv);

  attn_mfma8<<<544, 512, 0, stream>>>(qb, kb, vt, mask, yb, ep, emb_b, eb);

  ln2_kernel<<<BT_ROWS, 256, 0, stream>>>(yb, sb_w, sb_b, eb, gb);

  gemm_out<<<512, 256, 0, stream>>>(gb, owt, out_b, x, out);
}

// Round 18
// 186.503 us; speedup vs baseline: 1.0917x; 1.0917x over previous
//
#include <hip/hip_runtime.h>
#include <cstddef>
#include <cstdint>

#define B_SZ 8
#define T_SEQ 1024
#define D_MODEL 1024
#define NH 16
#define HD 64
#define TE_DIM 2048
#define BT_ROWS 8192

typedef short bf16x8 __attribute__((ext_vector_type(8)));
typedef float f32x4 __attribute__((ext_vector_type(4)));

#define MFMA16(a, b, c) __builtin_amdgcn_mfma_f32_16x16x32_bf16(a, b, c, 0, 0, 0)
#define EXP2(x) __builtin_amdgcn_exp2f(x)

__device__ inline unsigned short f2b(float f) {
  union { float f; unsigned u; } v; v.f = f;
  unsigned r = v.u + 0x7FFF + ((v.u >> 16) & 1);
  return (unsigned short)(r >> 16);
}

__device__ inline float b2f(unsigned short u) {
  union { unsigned u; float f; } v; v.u = ((unsigned)u) << 16; return v.f;
}

__device__ inline unsigned cvtpk(float a, float b) {
  unsigned r;
  asm("v_cvt_pk_bf16_f32 %0, %1, %2" : "=v"(r) : "v"(a), "v"(b));
  return r;
}

__device__ inline float max3f(float a, float b, float c) {
  return fmaxf(fmaxf(a, b), c);
}

__device__ inline void gll16(const void* g, void* l) {
  __builtin_amdgcn_global_load_lds(
      (const __attribute__((address_space(1))) unsigned int*)g,
      (__attribute__((address_space(3))) unsigned int*)l, 16, 0, 0);
}

// --- prep: ln (0..8191) + transposes (8192..12287) + emb_partial (12288..12415)
__global__ __launch_bounds__(256) void prep_kernel(
    const float* __restrict__ x, const float* __restrict__ norm_w,
    const float* __restrict__ norm_b, unsigned short* __restrict__ xn,
    const float* __restrict__ s0, const float* __restrict__ s1,
    const float* __restrict__ s2, const float* __restrict__ s3,
    unsigned short* __restrict__ d0, unsigned short* __restrict__ d1,
    unsigned short* __restrict__ d2, unsigned short* __restrict__ d3,
    const float* __restrict__ emb, const float* __restrict__ emb_w,
    float* __restrict__ partial)
{
  __shared__ float red[8];
  __shared__ float sT[32][33];
  __shared__ float ses[B_SZ][32];
  int bid = blockIdx.x;
  int tid = threadIdx.x;
  if (bid < BT_ROWS) {
    int row = bid;
    const float* xr = x + (size_t)row * D_MODEL;
    float4 xv = *(const float4*)&xr[tid * 4];
    float s  = xv.x + xv.y + xv.z + xv.w;
    float ss = xv.x*xv.x + xv.y*xv.y + xv.z*xv.z + xv.w*xv.w;
    #pragma unroll
    for (int off = 32; off; off >>= 1) {
      s  += __shfl_xor(s, off);
      ss += __shfl_xor(ss, off);
    }
    int wv = tid >> 6;
    if ((tid & 63) == 0) { red[wv] = s; red[4 + wv] = ss; }
    __syncthreads();
    s  = red[0] + red[1] + red[2] + red[3];
    ss = red[4] + red[5] + red[6] + red[7];
    float mean = s * (1.f / D_MODEL);
    float var  = ss * (1.f / D_MODEL) - mean * mean;
    float inv  = rsqrtf(var + 1e-5f);
    float4 w4 = *(const float4*)&norm_w[tid * 4];
    float4 b4 = *(const float4*)&norm_b[tid * 4];
    ushort4 o;
    o.x = f2b((xv.x - mean) * inv * w4.x + b4.x);
    o.y = f2b((xv.y - mean) * inv * w4.y + b4.y);
    o.z = f2b((xv.z - mean) * inv * w4.z + b4.z);
    o.w = f2b((xv.w - mean) * inv * w4.w + b4.w);
    int kg = tid >> 4, cb = (tid >> 1) & 7, e = (tid & 1) * 4;
    int col = kg * 64 + ((cb ^ (row & 7)) * 8) + e;
    *(ushort4*)&xn[(size_t)row * D_MODEL + col] = o;
  } else if (bid < BT_ROWS + 4096) {
    int tb = bid - BT_ROWS;
    int z = tb >> 10, yy = (tb >> 5) & 31, xx = tb & 31;
    const float* in = z == 0 ? s0 : z == 1 ? s1 : z == 2 ? s2 : s3;
    unsigned short* out = z == 0 ? d0 : z == 1 ? d1 : z == 2 ? d2 : d3;
    int tx = tid & 31, ty = tid >> 5;
    int r0 = yy * 32, c0 = xx * 32;
    #pragma unroll
    for (int rr = 0; rr < 4; ++rr)
      sT[ty + rr * 8][tx] = in[(size_t)(r0 + ty + rr * 8) * D_MODEL + c0 + tx];
    __syncthreads();
    int k = r0 + tx;
    int kg = k >> 6, cb = (k >> 3) & 7, e = k & 7;
    #pragma unroll
    for (int rr = 0; rr < 4; ++rr) {
      int n = c0 + ty + rr * 8;
      int col = kg * 64 + ((cb ^ (n & 7)) * 8) + e;
      out[(size_t)n * D_MODEL + col] = f2b(sT[tx][ty + rr * 8]);
    }
  } else {
    int tb2 = bid - (BT_ROWS + 4096);   // 0..127
    int colb = tb2 & 1, kb = tb2 >> 1;
    int t0 = kb * 32;
    {
      int b = tid >> 5, t = tid & 31;
      float v = emb[b * TE_DIM + t0 + t];
      ses[b][t] = v / (1.f + __expf(-v));
    }
    __syncthreads();
    int n = colb * 1024 + tid * 4;
    f32x4 acc[B_SZ];
    #pragma unroll
    for (int b = 0; b < B_SZ; ++b) acc[b] = (f32x4){0.f, 0.f, 0.f, 0.f};
    #pragma unroll 4
    for (int t = 0; t < 32; ++t) {
      f32x4 wv = *(const f32x4*)&emb_w[(size_t)(t0 + t) * (2 * D_MODEL) + n];
      #pragma unroll
      for (int b = 0; b < B_SZ; ++b) {
        float s = ses[b][t];
        acc[b][0] = fmaf(s, wv[0], acc[b][0]);
        acc[b][1] = fmaf(s, wv[1], acc[b][1]);
        acc[b][2] = fmaf(s, wv[2], acc[b][2]);
        acc[b][3] = fmaf(s, wv[3], acc[b][3]);
      }
    }
    #pragma unroll
    for (int b = 0; b < B_SZ; ++b)
      *(f32x4*)&partial[((size_t)kb * B_SZ + b) * (2 * D_MODEL) + n] = acc[b];
  }
}

// ------------- pipelined 256x128 QKV GEMM, 3-slot LDS ring (66us, pure) -----
__global__ __launch_bounds__(512, 2) void gemm_qkv8(
    const unsigned short* __restrict__ A, const unsigned short* __restrict__ W,
    const float* __restrict__ b0, const float* __restrict__ b1,
    const float* __restrict__ b2, const float* __restrict__ mask,
    unsigned short* __restrict__ O)
{
  const int K = 1024;
  __shared__ __align__(16) unsigned short SA[3][256 * 64];  // 96 KB
  __shared__ __align__(16) unsigned short SB[3][128 * 64];  // 48 KB
  int tid = threadIdx.x;
  int wid = tid >> 6, lane = tid & 63, g = lane >> 4, lq = lane & 15;
  int wm = wid >> 1, wn = wid & 1;
  int bid = blockIdx.x;
  int xcd = bid & 7, ii = bid >> 3;
  int mt = xcd * 4 + (ii & 3), nt = ii >> 2;
  int m0 = mt * 256;
  int wg = nt >> 3;
  int n0 = (nt & 7) * 128;
  const unsigned short* Bt = W + ((size_t)wg << 20);
  const float* bias = wg == 0 ? b0 : wg == 1 ? b1 : b2;

  f32x4 acc[4][4];
  #pragma unroll
  for (int i = 0; i < 4; ++i)
    #pragma unroll
    for (int j = 0; j < 4; ++j)
      acc[i][j] = (f32x4){0.f, 0.f, 0.f, 0.f};

  const unsigned short* aSrc = A + (size_t)(m0 + (tid >> 3)) * K + (tid & 7) * 8;
  const unsigned short* bSrc = Bt + (size_t)(n0 + (tid >> 3)) * K + (tid & 7) * 8;

  #define STAGE8(slot, t)                                                      \
    {                                                                          \
      size_t ko = (size_t)(t) * 64;                                            \
      _Pragma("unroll")                                                        \
      for (int i2 = 0; i2 < 4; ++i2)                                           \
        gll16(aSrc + ko + (size_t)i2 * 64 * K,                                 \
              (char*)&SA[slot][0] + tid * 16 + i2 * 8192);                     \
      _Pragma("unroll")                                                        \
      for (int i2 = 0; i2 < 2; ++i2)                                           \
        gll16(bSrc + ko + (size_t)i2 * 64 * K,                                 \
              (char*)&SB[slot][0] + tid * 16 + i2 * 8192);                     \
    }

  STAGE8(0, 0)
  STAGE8(1, 1)
  asm volatile("s_waitcnt vmcnt(6)" ::: "memory");
  asm volatile("s_barrier" ::: "memory");

  int cA0 = (g ^ (lq & 7)) * 16;
  int cA1 = ((4 + g) ^ (lq & 7)) * 16;

  #pragma unroll
  for (int t = 0; t < 16; ++t) {
    const char* sa = (const char*)&SA[t % 3][0];
    const char* sb = (const char*)&SB[t % 3][0];
    bf16x8 af[4][2], bf[4][2];
    #pragma unroll
    for (int i = 0; i < 4; ++i) {
      int ra = wm * 64 + i * 16 + lq;
      af[i][0] = *(const bf16x8*)(sa + ra * 128 + cA0);
      af[i][1] = *(const bf16x8*)(sa + ra * 128 + cA1);
      int rb = wn * 64 + i * 16 + lq;
      bf[i][0] = *(const bf16x8*)(sb + rb * 128 + cA0);
      bf[i][1] = *(const bf16x8*)(sb + rb * 128 + cA1);
    }
    if (t < 14) {
      STAGE8((t + 2) % 3, t + 2)
      asm volatile("s_waitcnt vmcnt(6)" ::: "memory");
    } else if (t == 14) {
      asm volatile("s_waitcnt vmcnt(0)" ::: "memory");
    }
    __builtin_amdgcn_s_setprio(1);
    #pragma unroll
    for (int i = 0; i < 4; ++i)
      #pragma unroll
      for (int j = 0; j < 4; ++j) {
        acc[i][j] = MFMA16(af[i][0], bf[j][0], acc[i][j]);
        acc[i][j] = MFMA16(af[i][1], bf[j][1], acc[i][j]);
      }
    __builtin_amdgcn_s_setprio(0);
    if (t < 15) asm volatile("s_barrier" ::: "memory");
  }
  #undef STAGE8

  int colbase = n0 + wn * 64;
  #pragma unroll
  for (int i = 0; i < 4; ++i) {
    int mrow0 = m0 + wm * 64 + i * 16 + g * 4;
    #pragma unroll
    for (int j = 0; j < 4; ++j) {
      int n = colbase + j * 16 + lq;
      float bv = bias[n];
      int h = n >> 6, dd = n & 63;
      if (wg < 2) {
        float scale = wg == 0 ? 1.44269504f : 1.0f;  // Q pre-scaled for exp2
        unsigned short* Cb = O + ((size_t)wg << 23);
        #pragma unroll
        for (int rr = 0; rr < 4; ++rr) {
          int m = mrow0 + rr;
          int b = m >> 10, tt = m & 1023;
          Cb[((size_t)((b * NH + h) * T_SEQ + tt)) * HD + dd] = f2b((acc[i][j][rr] + bv) * scale);
        }
      } else {
        unsigned short* Cb = O + ((size_t)2 << 23);
        int b = mrow0 >> 10, tt = mrow0 & 1023;
        ushort4 pk;
        unsigned short* pp = (unsigned short*)&pk;
        #pragma unroll
        for (int rr = 0; rr < 4; ++rr)
          pp[rr] = f2b((acc[i][j][rr] + bv) * mask[mrow0 + rr]);
        *(ushort4*)&Cb[((size_t)((b * NH + h) * HD + dd)) * T_SEQ + tt] = pk;
      }
    }
  }
}

// ---------------- out GEMM (proven 128x128 / 4-wave, ~24us) --------
__global__ __launch_bounds__(256) void gemm_out(
    const unsigned short* __restrict__ A, const unsigned short* __restrict__ Bt,
    const float* __restrict__ bias, const float* __restrict__ resid,
    float* __restrict__ C)
{
  const int K = 1024;
  __shared__ __align__(16) unsigned short As[128 * 64];
  __shared__ __align__(16) unsigned short Bs[128 * 64];
  int l = blockIdx.x;
  int xcd = l & 7, ii = l >> 3;
  int mt = xcd * 8 + (ii & 7), nt = ii >> 3;
  int m0 = mt * 128, n0 = nt * 128;

  int tid = threadIdx.x;
  int lane = tid & 63, w = tid >> 6;
  int g = lane >> 4, lq = lane & 15;
  int wr = w >> 1, wc = w & 1;
  f32x4 acc[4][4];
  #pragma unroll
  for (int i = 0; i < 4; ++i)
    #pragma unroll
    for (int j = 0; j < 4; ++j)
      acc[i][j] = (f32x4){0.f, 0.f, 0.f, 0.f};

  const unsigned short* aSrc = A + (size_t)(m0 + (tid >> 3)) * K + (tid & 7) * 8;
  const unsigned short* bSrc = Bt + (size_t)(n0 + (tid >> 3)) * K + (tid & 7) * 8;
  char* aDst = (char*)As + tid * 16;
  char* bDst = (char*)Bs + tid * 16;

  for (int k0 = 0; k0 < K; k0 += 64) {
    #pragma unroll
    for (int it = 0; it < 4; ++it) {
      gll16(aSrc + k0 + it * 32 * K, aDst + it * 4096);
      gll16(bSrc + k0 + it * 32 * K, bDst + it * 4096);
    }
    __syncthreads();
    #pragma unroll
    for (int kh = 0; kh < 2; ++kh) {
      bf16x8 af[4], bfr[4];
      #pragma unroll
      for (int i = 0; i < 4; ++i) {
        int ra = wr * 64 + i * 16 + lq;
        af[i] = *(const bf16x8*)((const char*)As + ra * 128 + (((kh * 4 + g) ^ (ra & 7)) * 16));
        int rb = wc * 64 + i * 16 + lq;
        bfr[i] = *(const bf16x8*)((const char*)Bs + rb * 128 + (((kh * 4 + g) ^ (rb & 7)) * 16));
      }
      #pragma unroll
      for (int i = 0; i < 4; ++i)
        #pragma unroll
        for (int j = 0; j < 4; ++j)
          acc[i][j] = MFMA16(af[i], bfr[j], acc[i][j]);
    }
    __syncthreads();
  }

  int colbase = n0 + wc * 64;
  #pragma unroll
  for (int i = 0; i < 4; ++i) {
    int mrow0 = m0 + wr * 64 + i * 16 + g * 4;
    #pragma unroll
    for (int j = 0; j < 4; ++j) {
      int n = colbase + j * 16 + lq;
      float bv = bias[n];
      #pragma unroll
      for (int rr = 0; rr < 4; ++rr) {
        int m = mrow0 + rr;
        C[(size_t)m * D_MODEL + n] = acc[i][j][rr] + bv + resid[(size_t)m * D_MODEL + n];
      }
    }
  }
}

// ------- MFMA flash attention v7 (blocks 0..511) + emb_reduce (512..575) ----
__global__ __launch_bounds__(256, 2) void attn_mfma7(
    const unsigned short* __restrict__ Q, const unsigned short* __restrict__ K,
    const unsigned short* __restrict__ Vt, const float* __restrict__ mask,
    unsigned short* __restrict__ y,
    const float* __restrict__ partial, const float* __restrict__ emb_b,
    float* __restrict__ e)
{
  __shared__ __align__(16) unsigned short SM[32768];   // 64 KB total
  int tid = threadIdx.x;
  int bid = blockIdx.x;

  if (bid >= 512) {
    // ---------------- emb_reduce ----------------
    int idx = (bid - 512) * 256 + tid;
    int b = idx >> 11, n = idx & 2047;
    float acc = emb_b[n];
    #pragma unroll 8
    for (int kb = 0; kb < 64; ++kb)
      acc += partial[((size_t)kb * B_SZ + b) * (2 * D_MODEL) + n];
    e[b * (2 * D_MODEL) + n] = acc;
    return;
  }

  unsigned short* Kb = SM;            // [2][4096]
  unsigned short* Vb = SM + 8192;     // [2][4096]
  unsigned short* Pb = SM + 16384;    // [4 waves][4 qa][1024]

  int w = tid >> 6, lane = tid & 63;
  int g = lane >> 4, lq = lane & 15;
  int lid = (bid & 7) * 64 + (bid >> 3);   // XCD remap
  int qb = lid & 3, h = (lid >> 2) & 15, b = lid >> 6;
  int q0 = qb * 256 + w * 64;
  size_t hb = ((size_t)(b * NH + h)) * T_SEQ * HD;

  bf16x8 bq[4][2];
  #pragma unroll
  for (int qa = 0; qa < 4; ++qa)
    #pragma unroll
    for (int kh = 0; kh < 2; ++kh)
      bq[qa][kh] = *(const bf16x8*)(Q + hb + (size_t)(q0 + qa * 16 + lq) * HD + kh * 32 + g * 8);

  bf16x8 ones;
  #pragma unroll
  for (int i = 0; i < 8; ++i) ones[i] = (short)16256;  // bf16 1.0

  const char* kBase = (const char*)(K + hb) + lq * 128 + g * 16;
  const char* vBase = (const char*)(Vt + hb) + lq * 2048 + g * 16;
  int c0 = 2 * w, c1 = 2 * w + 1;
  const char* kS0 = kBase + (c0 >> 1) * 2048 + (c0 & 1) * 64;
  const char* kS1 = kBase + (c1 >> 1) * 2048 + (c1 & 1) * 64;
  const char* vS0 = vBase + (c0 >> 1) * 32768 + (c0 & 1) * 64;
  const char* vS1 = vBase + (c1 >> 1) * 32768 + (c1 & 1) * 64;

  f32x4 o[4][4];   // [dt][qa]
  f32x4 osum[4];   // [qa] row-sum accumulator
  #pragma unroll
  for (int qa = 0; qa < 4; ++qa) {
    osum[qa] = (f32x4){0.f, 0.f, 0.f, 0.f};
    #pragma unroll
    for (int dt = 0; dt < 4; ++dt)
      o[dt][qa] = (f32x4){0.f, 0.f, 0.f, 0.f};
  }
  float mrun[4] = {-3.0e38f, -3.0e38f, -3.0e38f, -3.0e38f};
  const float* maskb = mask + b * T_SEQ;

  gll16(kS0, Kb + c0 * 512);
  gll16(kS1, Kb + c1 * 512);
  gll16(vS0, Vb + c0 * 512);
  gll16(vS1, Vb + c1 * 512);
  __syncthreads();

  for (int t = 0; t < 16; ++t) {
    int cur = t & 1;
    int kv0 = t * 64;
    if (t < 15) {
      int nxt = cur ^ 1;
      size_t ko = (size_t)(kv0 + 64) * 128;
      size_t vo = (size_t)(kv0 + 64) * 2;
      gll16(kS0 + ko, Kb + nxt * 4096 + c0 * 512);
      gll16(kS1 + ko, Kb + nxt * 4096 + c1 * 512);
      gll16(vS0 + vo, Vb + nxt * 4096 + c0 * 512);
      gll16(vS1 + vo, Vb + nxt * 4096 + c1 * 512);
    }
    const unsigned short* Kc = Kb + cur * 4096;
    const unsigned short* Vc = Vb + cur * 4096;

    f32x4 mbv[4];
    #pragma unroll
    for (int kt = 0; kt < 4; ++kt) {
      float4 mk = *(const float4*)&maskb[kv0 + kt * 16 + g * 4];
      mbv[kt][0] = fmaf(mk.x, 1500000.f, -1500000.f);
      mbv[kt][1] = fmaf(mk.y, 1500000.f, -1500000.f);
      mbv[kt][2] = fmaf(mk.z, 1500000.f, -1500000.f);
      mbv[kt][3] = fmaf(mk.w, 1500000.f, -1500000.f);
    }

    bf16x8 kf[4][2];
    #pragma unroll
    for (int kt = 0; kt < 4; ++kt)
      #pragma unroll
      for (int kh = 0; kh < 2; ++kh)
        kf[kt][kh] = *(const bf16x8*)(Kc + (kt * 2 + kh) * 512 + lane * 8);

    f32x4 st[4][4];
    __builtin_amdgcn_s_setprio(1);
    #pragma unroll
    for (int kt = 0; kt < 4; ++kt)
      #pragma unroll
      for (int qa = 0; qa < 4; ++qa) {
        st[kt][qa] = MFMA16(kf[kt][0], bq[qa][0], mbv[kt]);   // bias as C-init
        st[kt][qa] = MFMA16(kf[kt][1], bq[qa][1], st[kt][qa]);
      }
    __builtin_amdgcn_s_setprio(0);

    bf16x8 vf[4][2];
    #pragma unroll
    for (int dt = 0; dt < 4; ++dt)
      #pragma unroll
      for (int kh = 0; kh < 2; ++kh)
        vf[dt][kh] = *(const bf16x8*)(Vc + (dt * 2 + kh) * 512 + lane * 8);

    float tmax[4];
    #pragma unroll
    for (int qa = 0; qa < 4; ++qa) {
      float m0v = max3f(st[0][qa][0], st[0][qa][1], st[0][qa][2]);
      float m1v = max3f(st[0][qa][3], st[1][qa][0], st[1][qa][1]);
      float m2v = max3f(st[1][qa][2], st[1][qa][3], st[2][qa][0]);
      float m3v = max3f(st[2][qa][1], st[2][qa][2], st[2][qa][3]);
      float m4v = max3f(st[3][qa][0], st[3][qa][1], st[3][qa][2]);
      float t0v = max3f(m0v, m1v, st[3][qa][3]);
      float t1v = max3f(m2v, m3v, m4v);
      float tm = fmaxf(t0v, t1v);
      tm = fmaxf(tm, __shfl_xor(tm, 16));
      tm = fmaxf(tm, __shfl_xor(tm, 32));
      tmax[qa] = tm;
    }
    bool need = false;
    #pragma unroll
    for (int qa = 0; qa < 4; ++qa) need = need || (tmax[qa] > mrun[qa] + 11.5f);
    if (__any((int)need)) {
      #pragma unroll
      for (int qa = 0; qa < 4; ++qa) {
        float mnew = fmaxf(mrun[qa], tmax[qa]);
        float corr = EXP2(mrun[qa] - mnew);
        osum[qa][0] *= corr; osum[qa][1] *= corr;
        osum[qa][2] *= corr; osum[qa][3] *= corr;
        #pragma unroll
        for (int dt = 0; dt < 4; ++dt) {
          o[dt][qa][0] *= corr; o[dt][qa][1] *= corr;
          o[dt][qa][2] *= corr; o[dt][qa][3] *= corr;
        }
        mrun[qa] = mnew;
      }
    }
    #pragma unroll
    for (int qa = 0; qa < 4; ++qa)
      #pragma unroll
      for (int kt = 0; kt < 4; ++kt)
        #pragma unroll
        for (int r = 0; r < 4; ++r)
          st[kt][qa][r] = EXP2(st[kt][qa][r] - mrun[qa]);

    #pragma unroll
    for (int qa = 0; qa < 4; ++qa) {
      unsigned short* Pq = Pb + (w * 4 + qa) * 1024;
      #pragma unroll
      for (int kt = 0; kt < 4; ++kt) {
        uint2 pk2;
        pk2.x = cvtpk(st[kt][qa][0], st[kt][qa][1]);
        pk2.y = cvtpk(st[kt][qa][2], st[kt][qa][3]);
        *(uint2*)((char*)Pq + lq * 128 +
                  (((kt * 2 + (g >> 1)) ^ (lq & 7)) * 16) + (g & 1) * 8) = pk2;
      }
    }

    __builtin_amdgcn_s_setprio(1);
    #pragma unroll
    for (int qa = 0; qa < 4; ++qa) {
      const unsigned short* Pq = Pb + (w * 4 + qa) * 1024;
      #pragma unroll
      for (int kh = 0; kh < 2; ++kh) {
        bf16x8 pa = *(const bf16x8*)((const char*)Pq + lq * 128 +
                                     (((kh * 4 + g) ^ (lq & 7)) * 16));
        osum[qa] = MFMA16(ones, pa, osum[qa]);   // l via matrix pipe
        #pragma unroll
        for (int dt = 0; dt < 4; ++dt)
          o[dt][qa] = MFMA16(vf[dt][kh], pa, o[dt][qa]);
      }
    }
    __builtin_amdgcn_s_setprio(0);

    __syncthreads();
  }

  unsigned short* sc = SM + w * 4096;
  #pragma unroll
  for (int qa = 0; qa < 4; ++qa) {
    float inv = 1.f / osum[qa][0];
    #pragma unroll
    for (int dt = 0; dt < 4; ++dt) {
      uint2 pk;
      pk.x = cvtpk(o[dt][qa][0] * inv, o[dt][qa][1] * inv);
      pk.y = cvtpk(o[dt][qa][2] * inv, o[dt][qa][3] * inv);
      *(uint2*)(sc + (qa * 16 + lq) * 64 + dt * 16 + g * 4) = pk;
    }
  }
  #pragma unroll
  for (int it = 0; it < 16; ++it) {
    int row = it * 4 + g;
    ushort4 v = *(const ushort4*)(sc + row * 64 + lq * 4);
    *(ushort4*)&y[(size_t)(b * T_SEQ + q0 + row) * D_MODEL + h * HD + lq * 4] = v;
  }
}

// -------- g = silu(LN(y)*(1+scale)+shift)  (bf16 in/out, swizzled out) ------
__global__ __launch_bounds__(256) void ln2_kernel(
    const unsigned short* __restrict__ y, const float* __restrict__ w,
    const float* __restrict__ b, const float* __restrict__ e,
    unsigned short* __restrict__ gout)
{
  __shared__ float red[8];
  int row = blockIdx.x;
  int tid = threadIdx.x;
  int bb = row >> 10;
  ushort4 u = *(const ushort4*)&y[(size_t)row * D_MODEL + tid * 4];
  float4 yv = {b2f(u.x), b2f(u.y), b2f(u.z), b2f(u.w)};
  float s  = yv.x + yv.y + yv.z + yv.w;
  float ss = yv.x*yv.x + yv.y*yv.y + yv.z*yv.z + yv.w*yv.w;
  #pragma unroll
  for (int off = 32; off; off >>= 1) {
    s  += __shfl_xor(s, off);
    ss += __shfl_xor(ss, off);
  }
  int wv = tid >> 6;
  if ((tid & 63) == 0) { red[wv] = s; red[4 + wv] = ss; }
  __syncthreads();
  s  = red[0] + red[1] + red[2] + red[3];
  ss = red[4] + red[5] + red[6] + red[7];
  float mean = s * (1.f / D_MODEL);
  float var  = ss * (1.f / D_MODEL) - mean * mean;
  float inv  = rsqrtf(var + 1e-5f);
  float vals[4] = {yv.x, yv.y, yv.z, yv.w};
  ushort4 o;
  unsigned short* op = (unsigned short*)&o;
  #pragma unroll
  for (int j = 0; j < 4; j++) {
    int c = tid * 4 + j;
    float val = (vals[j] - mean) * inv * w[c] + b[c];
    float sc = e[bb * (2 * D_MODEL) + c];
    float sh = e[bb * (2 * D_MODEL) + D_MODEL + c];
    val = val * (1.f + sc) + sh;
    op[j] = f2b(val / (1.f + __expf(-val)));
  }
  int kg = tid >> 4, cb = (tid >> 1) & 7, ee = (tid & 1) * 4;
  int col = kg * 64 + ((cb ^ (row & 7)) * 8) + ee;
  *(ushort4*)&gout[(size_t)row * D_MODEL + col] = o;
}

extern "C" void kernel_launch(void* const* d_in, const int* in_sizes, int n_in,
                              void* d_out, int out_size, void* d_ws, size_t ws_size,
                              hipStream_t stream) {
  const float* x      = (const float*)d_in[0];
  const float* emb    = (const float*)d_in[1];
  const float* mask   = (const float*)d_in[2];
  const float* norm_w = (const float*)d_in[3];
  const float* norm_b = (const float*)d_in[4];
  const float* q_w    = (const float*)d_in[5];
  const float* q_b    = (const float*)d_in[6];
  const float* k_w    = (const float*)d_in[7];
  const float* k_b    = (const float*)d_in[8];
  const float* v_w    = (const float*)d_in[9];
  const float* v_b    = (const float*)d_in[10];
  const float* emb_w  = (const float*)d_in[11];
  const float* emb_b  = (const float*)d_in[12];
  const float* sb_w   = (const float*)d_in[13];
  const float* sb_b   = (const float*)d_in[14];
  const float* out_w  = (const float*)d_in[15];
  const float* out_b  = (const float*)d_in[16];
  float* out = (float*)d_out;

  char* ws = (char*)d_ws;
  const size_t MB = 1u << 20;
  unsigned short* xn   = (unsigned short*)(ws);             // 16 MB bf16 swz
  unsigned short* qkv  = (unsigned short*)(ws + 16 * MB);   // 48 MB: qb|kb|vt
  unsigned short* qb   = qkv;
  unsigned short* kb   = qkv + (1u << 23);
  unsigned short* vt   = qkv + (2u << 23);
  unsigned short* yb   = (unsigned short*)(ws + 64 * MB);   // 16 MB bf16 y
  unsigned short* gb   = (unsigned short*)(ws + 96 * MB);   // 16 MB bf16 swz
  float*          ep   = (float*)(ws + 96 * MB);            // 4 MB (dead before gb)
  unsigned short* w3t  = (unsigned short*)(ws + 112 * MB);  // 6 MB: qwt|kwt|vwt
  unsigned short* owt  = (unsigned short*)(ws + 118 * MB);  // 2 MB
  float*          eb   = (float*)(ws + 120 * MB);           // 64 KB

  prep_kernel<<<BT_ROWS + 4096 + 128, 256, 0, stream>>>(
      x, norm_w, norm_b, xn,
      q_w, k_w, v_w, out_w,
      w3t, w3t + (1u << 20), w3t + (2u << 20), owt,
      emb, emb_w, ep);

  gemm_qkv8<<<768, 512, 0, stream>>>(xn, w3t, q_b, k_b, v_b, mask, qkv);

  attn_mfma7<<<576, 256, 0, stream>>>(qb, kb, vt, mask, yb, ep, emb_b, eb);

  ln2_kernel<<<BT_ROWS, 256, 0, stream>>>(yb, sb_w, sb_b, eb, gb);

  gemm_out<<<512, 256, 0, stream>>>(gb, owt, out_b, x, out);
}

// Round 19
// 174.510 us; speedup vs baseline: 1.1667x; 1.0687x over previous
//
#include <hip/hip_runtime.h>
#include <cstddef>
#include <cstdint>

#define B_SZ 8
#define T_SEQ 1024
#define D_MODEL 1024
#define NH 16
#define HD 64
#define TE_DIM 2048
#define BT_ROWS 8192

typedef short bf16x8 __attribute__((ext_vector_type(8)));
typedef float f32x4 __attribute__((ext_vector_type(4)));

#define MFMA16(a, b, c) __builtin_amdgcn_mfma_f32_16x16x32_bf16(a, b, c, 0, 0, 0)
#define EXP2(x) __builtin_amdgcn_exp2f(x)

__device__ inline unsigned short f2b(float f) {
  union { float f; unsigned u; } v; v.f = f;
  unsigned r = v.u + 0x7FFF + ((v.u >> 16) & 1);
  return (unsigned short)(r >> 16);
}

__device__ inline float b2f(unsigned short u) {
  union { unsigned u; float f; } v; v.u = ((unsigned)u) << 16; return v.f;
}

__device__ inline unsigned cvtpk(float a, float b) {
  unsigned r;
  asm("v_cvt_pk_bf16_f32 %0, %1, %2" : "=v"(r) : "v"(a), "v"(b));
  return r;
}

__device__ inline float max3f(float a, float b, float c) {
  return fmaxf(fmaxf(a, b), c);
}

__device__ inline void gll16(const void* g, void* l) {
  __builtin_amdgcn_global_load_lds(
      (const __attribute__((address_space(1))) unsigned int*)g,
      (__attribute__((address_space(3))) unsigned int*)l, 16, 0, 0);
}

// ------- prep: ln (blocks 0..8191) + 4 weight transposes (8192..12287) ------
__global__ __launch_bounds__(256) void prep_kernel(
    const float* __restrict__ x, const float* __restrict__ norm_w,
    const float* __restrict__ norm_b, unsigned short* __restrict__ xn,
    const float* __restrict__ s0, const float* __restrict__ s1,
    const float* __restrict__ s2, const float* __restrict__ s3,
    unsigned short* __restrict__ d0, unsigned short* __restrict__ d1,
    unsigned short* __restrict__ d2, unsigned short* __restrict__ d3)
{
  __shared__ float red[8];
  __shared__ float sT[32][33];
  int bid = blockIdx.x;
  int tid = threadIdx.x;
  if (bid < BT_ROWS) {
    int row = bid;
    const float* xr = x + (size_t)row * D_MODEL;
    float4 xv = *(const float4*)&xr[tid * 4];
    float s  = xv.x + xv.y + xv.z + xv.w;
    float ss = xv.x*xv.x + xv.y*xv.y + xv.z*xv.z + xv.w*xv.w;
    #pragma unroll
    for (int off = 32; off; off >>= 1) {
      s  += __shfl_xor(s, off);
      ss += __shfl_xor(ss, off);
    }
    int wv = tid >> 6;
    if ((tid & 63) == 0) { red[wv] = s; red[4 + wv] = ss; }
    __syncthreads();
    s  = red[0] + red[1] + red[2] + red[3];
    ss = red[4] + red[5] + red[6] + red[7];
    float mean = s * (1.f / D_MODEL);
    float var  = ss * (1.f / D_MODEL) - mean * mean;
    float inv  = rsqrtf(var + 1e-5f);
    float4 w4 = *(const float4*)&norm_w[tid * 4];
    float4 b4 = *(const float4*)&norm_b[tid * 4];
    ushort4 o;
    o.x = f2b((xv.x - mean) * inv * w4.x + b4.x);
    o.y = f2b((xv.y - mean) * inv * w4.y + b4.y);
    o.z = f2b((xv.z - mean) * inv * w4.z + b4.z);
    o.w = f2b((xv.w - mean) * inv * w4.w + b4.w);
    int kg = tid >> 4, cb = (tid >> 1) & 7, e = (tid & 1) * 4;
    int col = kg * 64 + ((cb ^ (row & 7)) * 8) + e;
    *(ushort4*)&xn[(size_t)row * D_MODEL + col] = o;
  } else {
    int tb = bid - BT_ROWS;
    int z = tb >> 10, yy = (tb >> 5) & 31, xx = tb & 31;
    const float* in = z == 0 ? s0 : z == 1 ? s1 : z == 2 ? s2 : s3;
    unsigned short* out = z == 0 ? d0 : z == 1 ? d1 : z == 2 ? d2 : d3;
    int tx = tid & 31, ty = tid >> 5;
    int r0 = yy * 32, c0 = xx * 32;
    #pragma unroll
    for (int rr = 0; rr < 4; ++rr)
      sT[ty + rr * 8][tx] = in[(size_t)(r0 + ty + rr * 8) * D_MODEL + c0 + tx];
    __syncthreads();
    int k = r0 + tx;
    int kg = k >> 6, cb = (k >> 3) & 7, e = k & 7;
    #pragma unroll
    for (int rr = 0; rr < 4; ++rr) {
      int n = c0 + ty + rr * 8;
      int col = kg * 64 + ((cb ^ (n & 7)) * 8) + e;
      out[(size_t)n * D_MODEL + col] = f2b(sT[tx][ty + rr * 8]);
    }
  }
}

// --- QKV GEMM: blocks 0..63 emb_partial (HEAD, hides under GEMM), 64..831 ring
__global__ __launch_bounds__(512, 2) void gemm_qkv8(
    const unsigned short* __restrict__ A, const unsigned short* __restrict__ W,
    const float* __restrict__ b0, const float* __restrict__ b1,
    const float* __restrict__ b2, const float* __restrict__ mask,
    unsigned short* __restrict__ O,
    const float* __restrict__ emb, const float* __restrict__ emb_w,
    float* __restrict__ partial)
{
  const int K = 1024;
  __shared__ __align__(16) unsigned short SA[3][256 * 64];  // 96 KB
  __shared__ __align__(16) unsigned short SB[3][128 * 64];  // 48 KB
  int tid = threadIdx.x;
  int bid = blockIdx.x;

  if (bid < 64) {
    // ---------------- emb split-K partial (512-thread variant) ------------
    int kb = bid;                       // 0..63
    float* ses = (float*)&SA[0][0];     // [8][32] floats
    int t0 = kb * 32;
    if (tid < 256) {
      int b = tid >> 5, t = tid & 31;
      float v = emb[b * TE_DIM + t0 + t];
      ses[b * 32 + t] = v / (1.f + __expf(-v));
    }
    __syncthreads();
    int n = tid * 4;
    f32x4 acc[B_SZ];
    #pragma unroll
    for (int b = 0; b < B_SZ; ++b) acc[b] = (f32x4){0.f, 0.f, 0.f, 0.f};
    #pragma unroll 4
    for (int t = 0; t < 32; ++t) {
      f32x4 wv = *(const f32x4*)&emb_w[(size_t)(t0 + t) * (2 * D_MODEL) + n];
      #pragma unroll
      for (int b = 0; b < B_SZ; ++b) {
        float s = ses[b * 32 + t];
        acc[b][0] = fmaf(s, wv[0], acc[b][0]);
        acc[b][1] = fmaf(s, wv[1], acc[b][1]);
        acc[b][2] = fmaf(s, wv[2], acc[b][2]);
        acc[b][3] = fmaf(s, wv[3], acc[b][3]);
      }
    }
    #pragma unroll
    for (int b = 0; b < B_SZ; ++b)
      *(f32x4*)&partial[((size_t)kb * B_SZ + b) * (2 * D_MODEL) + n] = acc[b];
    return;
  }

  int gb_ = bid - 64;   // GEMM block index 0..767
  int wid = tid >> 6, lane = tid & 63, g = lane >> 4, lq = lane & 15;
  int wm = wid >> 1, wn = wid & 1;
  int xcd = gb_ & 7, ii = gb_ >> 3;
  int mt = xcd * 4 + (ii & 3), nt = ii >> 2;
  int m0 = mt * 256;
  int wg = nt >> 3;
  int n0 = (nt & 7) * 128;
  const unsigned short* Bt = W + ((size_t)wg << 20);
  const float* bias = wg == 0 ? b0 : wg == 1 ? b1 : b2;

  f32x4 acc[4][4];
  #pragma unroll
  for (int i = 0; i < 4; ++i)
    #pragma unroll
    for (int j = 0; j < 4; ++j)
      acc[i][j] = (f32x4){0.f, 0.f, 0.f, 0.f};

  const unsigned short* aSrc = A + (size_t)(m0 + (tid >> 3)) * K + (tid & 7) * 8;
  const unsigned short* bSrc = Bt + (size_t)(n0 + (tid >> 3)) * K + (tid & 7) * 8;

  #define STAGE8(slot, t)                                                      \
    {                                                                          \
      size_t ko = (size_t)(t) * 64;                                            \
      _Pragma("unroll")                                                        \
      for (int i2 = 0; i2 < 4; ++i2)                                           \
        gll16(aSrc + ko + (size_t)i2 * 64 * K,                                 \
              (char*)&SA[slot][0] + tid * 16 + i2 * 8192);                     \
      _Pragma("unroll")                                                        \
      for (int i2 = 0; i2 < 2; ++i2)                                           \
        gll16(bSrc + ko + (size_t)i2 * 64 * K,                                 \
              (char*)&SB[slot][0] + tid * 16 + i2 * 8192);                     \
    }

  STAGE8(0, 0)
  STAGE8(1, 1)
  asm volatile("s_waitcnt vmcnt(6)" ::: "memory");
  asm volatile("s_barrier" ::: "memory");

  int cA0 = (g ^ (lq & 7)) * 16;
  int cA1 = ((4 + g) ^ (lq & 7)) * 16;

  #pragma unroll
  for (int t = 0; t < 16; ++t) {
    const char* sa = (const char*)&SA[t % 3][0];
    const char* sb = (const char*)&SB[t % 3][0];
    bf16x8 af[4][2], bf[4][2];
    #pragma unroll
    for (int i = 0; i < 4; ++i) {
      int ra = wm * 64 + i * 16 + lq;
      af[i][0] = *(const bf16x8*)(sa + ra * 128 + cA0);
      af[i][1] = *(const bf16x8*)(sa + ra * 128 + cA1);
      int rb = wn * 64 + i * 16 + lq;
      bf[i][0] = *(const bf16x8*)(sb + rb * 128 + cA0);
      bf[i][1] = *(const bf16x8*)(sb + rb * 128 + cA1);
    }
    if (t < 14) {
      STAGE8((t + 2) % 3, t + 2)
      asm volatile("s_waitcnt vmcnt(6)" ::: "memory");
    } else if (t == 14) {
      asm volatile("s_waitcnt vmcnt(0)" ::: "memory");
    }
    __builtin_amdgcn_s_setprio(1);
    #pragma unroll
    for (int i = 0; i < 4; ++i)
      #pragma unroll
      for (int j = 0; j < 4; ++j) {
        acc[i][j] = MFMA16(af[i][0], bf[j][0], acc[i][j]);
        acc[i][j] = MFMA16(af[i][1], bf[j][1], acc[i][j]);
      }
    __builtin_amdgcn_s_setprio(0);
    if (t < 15) asm volatile("s_barrier" ::: "memory");
  }
  #undef STAGE8

  int colbase = n0 + wn * 64;
  #pragma unroll
  for (int i = 0; i < 4; ++i) {
    int mrow0 = m0 + wm * 64 + i * 16 + g * 4;
    #pragma unroll
    for (int j = 0; j < 4; ++j) {
      int n = colbase + j * 16 + lq;
      float bv = bias[n];
      int h = n >> 6, dd = n & 63;
      if (wg < 2) {
        float scale = wg == 0 ? 1.44269504f : 1.0f;  // Q pre-scaled for exp2
        unsigned short* Cb = O + ((size_t)wg << 23);
        #pragma unroll
        for (int rr = 0; rr < 4; ++rr) {
          int m = mrow0 + rr;
          int b = m >> 10, tt = m & 1023;
          Cb[((size_t)((b * NH + h) * T_SEQ + tt)) * HD + dd] = f2b((acc[i][j][rr] + bv) * scale);
        }
      } else {
        unsigned short* Cb = O + ((size_t)2 << 23);
        int b = mrow0 >> 10, tt = mrow0 & 1023;
        ushort4 pk;
        unsigned short* pp = (unsigned short*)&pk;
        #pragma unroll
        for (int rr = 0; rr < 4; ++rr)
          pp[rr] = f2b((acc[i][j][rr] + bv) * mask[mrow0 + rr]);
        *(ushort4*)&Cb[((size_t)((b * NH + h) * HD + dd)) * T_SEQ + tt] = pk;
      }
    }
  }
}

// ---------------- out GEMM (proven 128x128 / 4-wave, ~24us) --------
__global__ __launch_bounds__(256) void gemm_out(
    const unsigned short* __restrict__ A, const unsigned short* __restrict__ Bt,
    const float* __restrict__ bias, const float* __restrict__ resid,
    float* __restrict__ C)
{
  const int K = 1024;
  __shared__ __align__(16) unsigned short As[128 * 64];
  __shared__ __align__(16) unsigned short Bs[128 * 64];
  int l = blockIdx.x;
  int xcd = l & 7, ii = l >> 3;
  int mt = xcd * 8 + (ii & 7), nt = ii >> 3;
  int m0 = mt * 128, n0 = nt * 128;

  int tid = threadIdx.x;
  int lane = tid & 63, w = tid >> 6;
  int g = lane >> 4, lq = lane & 15;
  int wr = w >> 1, wc = w & 1;
  f32x4 acc[4][4];
  #pragma unroll
  for (int i = 0; i < 4; ++i)
    #pragma unroll
    for (int j = 0; j < 4; ++j)
      acc[i][j] = (f32x4){0.f, 0.f, 0.f, 0.f};

  const unsigned short* aSrc = A + (size_t)(m0 + (tid >> 3)) * K + (tid & 7) * 8;
  const unsigned short* bSrc = Bt + (size_t)(n0 + (tid >> 3)) * K + (tid & 7) * 8;
  char* aDst = (char*)As + tid * 16;
  char* bDst = (char*)Bs + tid * 16;

  for (int k0 = 0; k0 < K; k0 += 64) {
    #pragma unroll
    for (int it = 0; it < 4; ++it) {
      gll16(aSrc + k0 + it * 32 * K, aDst + it * 4096);
      gll16(bSrc + k0 + it * 32 * K, bDst + it * 4096);
    }
    __syncthreads();
    #pragma unroll
    for (int kh = 0; kh < 2; ++kh) {
      bf16x8 af[4], bfr[4];
      #pragma unroll
      for (int i = 0; i < 4; ++i) {
        int ra = wr * 64 + i * 16 + lq;
        af[i] = *(const bf16x8*)((const char*)As + ra * 128 + (((kh * 4 + g) ^ (ra & 7)) * 16));
        int rb = wc * 64 + i * 16 + lq;
        bfr[i] = *(const bf16x8*)((const char*)Bs + rb * 128 + (((kh * 4 + g) ^ (rb & 7)) * 16));
      }
      #pragma unroll
      for (int i = 0; i < 4; ++i)
        #pragma unroll
        for (int j = 0; j < 4; ++j)
          acc[i][j] = MFMA16(af[i], bfr[j], acc[i][j]);
    }
    __syncthreads();
  }

  int colbase = n0 + wc * 64;
  #pragma unroll
  for (int i = 0; i < 4; ++i) {
    int mrow0 = m0 + wr * 64 + i * 16 + g * 4;
    #pragma unroll
    for (int j = 0; j < 4; ++j) {
      int n = colbase + j * 16 + lq;
      float bv = bias[n];
      #pragma unroll
      for (int rr = 0; rr < 4; ++rr) {
        int m = mrow0 + rr;
        C[(size_t)m * D_MODEL + n] = acc[i][j][rr] + bv + resid[(size_t)m * D_MODEL + n];
      }
    }
  }
}

// --- attention: blocks 0..63 emb_reduce (HEAD), 64..575 attn v7 -------------
__global__ __launch_bounds__(256, 2) void attn_mfma7(
    const unsigned short* __restrict__ Q, const unsigned short* __restrict__ K,
    const unsigned short* __restrict__ Vt, const float* __restrict__ mask,
    unsigned short* __restrict__ y,
    const float* __restrict__ partial, const float* __restrict__ emb_b,
    float* __restrict__ e)
{
  __shared__ __align__(16) unsigned short SM[32768];   // 64 KB total
  int tid = threadIdx.x;
  int bid = blockIdx.x;

  if (bid < 64) {
    // ---------------- emb_reduce ----------------
    int idx = bid * 256 + tid;
    int b = idx >> 11, n = idx & 2047;
    float acc = emb_b[n];
    #pragma unroll 8
    for (int kb = 0; kb < 64; ++kb)
      acc += partial[((size_t)kb * B_SZ + b) * (2 * D_MODEL) + n];
    e[b * (2 * D_MODEL) + n] = acc;
    return;
  }

  int abid = bid - 64;   // attn block 0..511
  unsigned short* Kb = SM;            // [2][4096]
  unsigned short* Vb = SM + 8192;     // [2][4096]
  unsigned short* Pb = SM + 16384;    // [4 waves][4 qa][1024]

  int w = tid >> 6, lane = tid & 63;
  int g = lane >> 4, lq = lane & 15;
  int lid = (abid & 7) * 64 + (abid >> 3);   // XCD remap
  int qb = lid & 3, h = (lid >> 2) & 15, b = lid >> 6;
  int q0 = qb * 256 + w * 64;
  size_t hb = ((size_t)(b * NH + h)) * T_SEQ * HD;

  bf16x8 bq[4][2];
  #pragma unroll
  for (int qa = 0; qa < 4; ++qa)
    #pragma unroll
    for (int kh = 0; kh < 2; ++kh)
      bq[qa][kh] = *(const bf16x8*)(Q + hb + (size_t)(q0 + qa * 16 + lq) * HD + kh * 32 + g * 8);

  bf16x8 ones;
  #pragma unroll
  for (int i = 0; i < 8; ++i) ones[i] = (short)16256;  // bf16 1.0

  const char* kBase = (const char*)(K + hb) + lq * 128 + g * 16;
  const char* vBase = (const char*)(Vt + hb) + lq * 2048 + g * 16;
  int c0 = 2 * w, c1 = 2 * w + 1;
  const char* kS0 = kBase + (c0 >> 1) * 2048 + (c0 & 1) * 64;
  const char* kS1 = kBase + (c1 >> 1) * 2048 + (c1 & 1) * 64;
  const char* vS0 = vBase + (c0 >> 1) * 32768 + (c0 & 1) * 64;
  const char* vS1 = vBase + (c1 >> 1) * 32768 + (c1 & 1) * 64;

  f32x4 o[4][4];   // [dt][qa]
  f32x4 osum[4];   // [qa] row-sum accumulator
  #pragma unroll
  for (int qa = 0; qa < 4; ++qa) {
    osum[qa] = (f32x4){0.f, 0.f, 0.f, 0.f};
    #pragma unroll
    for (int dt = 0; dt < 4; ++dt)
      o[dt][qa] = (f32x4){0.f, 0.f, 0.f, 0.f};
  }
  float mrun[4] = {-3.0e38f, -3.0e38f, -3.0e38f, -3.0e38f};
  const float* maskb = mask + b * T_SEQ;

  gll16(kS0, Kb + c0 * 512);
  gll16(kS1, Kb + c1 * 512);
  gll16(vS0, Vb + c0 * 512);
  gll16(vS1, Vb + c1 * 512);
  __syncthreads();

  for (int t = 0; t < 16; ++t) {
    int cur = t & 1;
    int kv0 = t * 64;
    if (t < 15) {
      int nxt = cur ^ 1;
      size_t ko = (size_t)(kv0 + 64) * 128;
      size_t vo = (size_t)(kv0 + 64) * 2;
      gll16(kS0 + ko, Kb + nxt * 4096 + c0 * 512);
      gll16(kS1 + ko, Kb + nxt * 4096 + c1 * 512);
      gll16(vS0 + vo, Vb + nxt * 4096 + c0 * 512);
      gll16(vS1 + vo, Vb + nxt * 4096 + c1 * 512);
    }
    const unsigned short* Kc = Kb + cur * 4096;
    const unsigned short* Vc = Vb + cur * 4096;

    f32x4 mbv[4];
    #pragma unroll
    for (int kt = 0; kt < 4; ++kt) {
      float4 mk = *(const float4*)&maskb[kv0 + kt * 16 + g * 4];
      mbv[kt][0] = fmaf(mk.x, 1500000.f, -1500000.f);
      mbv[kt][1] = fmaf(mk.y, 1500000.f, -1500000.f);
      mbv[kt][2] = fmaf(mk.z, 1500000.f, -1500000.f);
      mbv[kt][3] = fmaf(mk.w, 1500000.f, -1500000.f);
    }

    bf16x8 kf[4][2];
    #pragma unroll
    for (int kt = 0; kt < 4; ++kt)
      #pragma unroll
      for (int kh = 0; kh < 2; ++kh)
        kf[kt][kh] = *(const bf16x8*)(Kc + (kt * 2 + kh) * 512 + lane * 8);

    f32x4 st[4][4];
    __builtin_amdgcn_s_setprio(1);
    #pragma unroll
    for (int kt = 0; kt < 4; ++kt)
      #pragma unroll
      for (int qa = 0; qa < 4; ++qa) {
        st[kt][qa] = MFMA16(kf[kt][0], bq[qa][0], mbv[kt]);   // bias as C-init
        st[kt][qa] = MFMA16(kf[kt][1], bq[qa][1], st[kt][qa]);
      }
    __builtin_amdgcn_s_setprio(0);

    bf16x8 vf[4][2];
    #pragma unroll
    for (int dt = 0; dt < 4; ++dt)
      #pragma unroll
      for (int kh = 0; kh < 2; ++kh)
        vf[dt][kh] = *(const bf16x8*)(Vc + (dt * 2 + kh) * 512 + lane * 8);

    float tmax[4];
    #pragma unroll
    for (int qa = 0; qa < 4; ++qa) {
      float m0v = max3f(st[0][qa][0], st[0][qa][1], st[0][qa][2]);
      float m1v = max3f(st[0][qa][3], st[1][qa][0], st[1][qa][1]);
      float m2v = max3f(st[1][qa][2], st[1][qa][3], st[2][qa][0]);
      float m3v = max3f(st[2][qa][1], st[2][qa][2], st[2][qa][3]);
      float m4v = max3f(st[3][qa][0], st[3][qa][1], st[3][qa][2]);
      float t0v = max3f(m0v, m1v, st[3][qa][3]);
      float t1v = max3f(m2v, m3v, m4v);
      float tm = fmaxf(t0v, t1v);
      tm = fmaxf(tm, __shfl_xor(tm, 16));
      tm = fmaxf(tm, __shfl_xor(tm, 32));
      tmax[qa] = tm;
    }
    bool need = false;
    #pragma unroll
    for (int qa = 0; qa < 4; ++qa) need = need || (tmax[qa] > mrun[qa] + 11.5f);
    if (__any((int)need)) {
      #pragma unroll
      for (int qa = 0; qa < 4; ++qa) {
        float mnew = fmaxf(mrun[qa], tmax[qa]);
        float corr = EXP2(mrun[qa] - mnew);
        osum[qa][0] *= corr; osum[qa][1] *= corr;
        osum[qa][2] *= corr; osum[qa][3] *= corr;
        #pragma unroll
        for (int dt = 0; dt < 4; ++dt) {
          o[dt][qa][0] *= corr; o[dt][qa][1] *= corr;
          o[dt][qa][2] *= corr; o[dt][qa][3] *= corr;
        }
        mrun[qa] = mnew;
      }
    }
    #pragma unroll
    for (int qa = 0; qa < 4; ++qa)
      #pragma unroll
      for (int kt = 0; kt < 4; ++kt)
        #pragma unroll
        for (int r = 0; r < 4; ++r)
          st[kt][qa][r] = EXP2(st[kt][qa][r] - mrun[qa]);

    #pragma unroll
    for (int qa = 0; qa < 4; ++qa) {
      unsigned short* Pq = Pb + (w * 4 + qa) * 1024;
      #pragma unroll
      for (int kt = 0; kt < 4; ++kt) {
        uint2 pk2;
        pk2.x = cvtpk(st[kt][qa][0], st[kt][qa][1]);
        pk2.y = cvtpk(st[kt][qa][2], st[kt][qa][3]);
        *(uint2*)((char*)Pq + lq * 128 +
                  (((kt * 2 + (g >> 1)) ^ (lq & 7)) * 16) + (g & 1) * 8) = pk2;
      }
    }

    __builtin_amdgcn_s_setprio(1);
    #pragma unroll
    for (int qa = 0; qa < 4; ++qa) {
      const unsigned short* Pq = Pb + (w * 4 + qa) * 1024;
      #pragma unroll
      for (int kh = 0; kh < 2; ++kh) {
        bf16x8 pa = *(const bf16x8*)((const char*)Pq + lq * 128 +
                                     (((kh * 4 + g) ^ (lq & 7)) * 16));
        osum[qa] = MFMA16(ones, pa, osum[qa]);   // l via matrix pipe
        #pragma unroll
        for (int dt = 0; dt < 4; ++dt)
          o[dt][qa] = MFMA16(vf[dt][kh], pa, o[dt][qa]);
      }
    }
    __builtin_amdgcn_s_setprio(0);

    __syncthreads();
  }

  unsigned short* sc = SM + w * 4096;
  #pragma unroll
  for (int qa = 0; qa < 4; ++qa) {
    float inv = 1.f / osum[qa][0];
    #pragma unroll
    for (int dt = 0; dt < 4; ++dt) {
      uint2 pk;
      pk.x = cvtpk(o[dt][qa][0] * inv, o[dt][qa][1] * inv);
      pk.y = cvtpk(o[dt][qa][2] * inv, o[dt][qa][3] * inv);
      *(uint2*)(sc + (qa * 16 + lq) * 64 + dt * 16 + g * 4) = pk;
    }
  }
  #pragma unroll
  for (int it = 0; it < 16; ++it) {
    int row = it * 4 + g;
    ushort4 v = *(const ushort4*)(sc + row * 64 + lq * 4);
    *(ushort4*)&y[(size_t)(b * T_SEQ + q0 + row) * D_MODEL + h * HD + lq * 4] = v;
  }
}

// -------- g = silu(LN(y)*(1+scale)+shift)  (bf16 in/out, swizzled out) ------
__global__ __launch_bounds__(256) void ln2_kernel(
    const unsigned short* __restrict__ y, const float* __restrict__ w,
    const float* __restrict__ b, const float* __restrict__ e,
    unsigned short* __restrict__ gout)
{
  __shared__ float red[8];
  int row = blockIdx.x;
  int tid = threadIdx.x;
  int bb = row >> 10;
  ushort4 u = *(const ushort4*)&y[(size_t)row * D_MODEL + tid * 4];
  float4 yv = {b2f(u.x), b2f(u.y), b2f(u.z), b2f(u.w)};
  float s  = yv.x + yv.y + yv.z + yv.w;
  float ss = yv.x*yv.x + yv.y*yv.y + yv.z*yv.z + yv.w*yv.w;
  #pragma unroll
  for (int off = 32; off; off >>= 1) {
    s  += __shfl_xor(s, off);
    ss += __shfl_xor(ss, off);
  }
  int wv = tid >> 6;
  if ((tid & 63) == 0) { red[wv] = s; red[4 + wv] = ss; }
  __syncthreads();
  s  = red[0] + red[1] + red[2] + red[3];
  ss = red[4] + red[5] + red[6] + red[7];
  float mean = s * (1.f / D_MODEL);
  float var  = ss * (1.f / D_MODEL) - mean * mean;
  float inv  = rsqrtf(var + 1e-5f);
  float vals[4] = {yv.x, yv.y, yv.z, yv.w};
  ushort4 o;
  unsigned short* op = (unsigned short*)&o;
  #pragma unroll
  for (int j = 0; j < 4; j++) {
    int c = tid * 4 + j;
    float val = (vals[j] - mean) * inv * w[c] + b[c];
    float sc = e[bb * (2 * D_MODEL) + c];
    float sh = e[bb * (2 * D_MODEL) + D_MODEL + c];
    val = val * (1.f + sc) + sh;
    op[j] = f2b(val / (1.f + __expf(-val)));
  }
  int kg = tid >> 4, cb = (tid >> 1) & 7, ee = (tid & 1) * 4;
  int col = kg * 64 + ((cb ^ (row & 7)) * 8) + ee;
  *(ushort4*)&gout[(size_t)row * D_MODEL + col] = o;
}

extern "C" void kernel_launch(void* const* d_in, const int* in_sizes, int n_in,
                              void* d_out, int out_size, void* d_ws, size_t ws_size,
                              hipStream_t stream) {
  const float* x      = (const float*)d_in[0];
  const float* emb    = (const float*)d_in[1];
  const float* mask   = (const float*)d_in[2];
  const float* norm_w = (const float*)d_in[3];
  const float* norm_b = (const float*)d_in[4];
  const float* q_w    = (const float*)d_in[5];
  const float* q_b    = (const float*)d_in[6];
  const float* k_w    = (const float*)d_in[7];
  const float* k_b    = (const float*)d_in[8];
  const float* v_w    = (const float*)d_in[9];
  const float* v_b    = (const float*)d_in[10];
  const float* emb_w  = (const float*)d_in[11];
  const float* emb_b  = (const float*)d_in[12];
  const float* sb_w   = (const float*)d_in[13];
  const float* sb_b   = (const float*)d_in[14];
  const float* out_w  = (const float*)d_in[15];
  const float* out_b  = (const float*)d_in[16];
  float* out = (float*)d_out;

  char* ws = (char*)d_ws;
  const size_t MB = 1u << 20;
  unsigned short* xn   = (unsigned short*)(ws);             // 16 MB bf16 swz
  unsigned short* qkv  = (unsigned short*)(ws + 16 * MB);   // 48 MB: qb|kb|vt
  unsigned short* qb   = qkv;
  unsigned short* kb   = qkv + (1u << 23);
  unsigned short* vt   = qkv + (2u << 23);
  unsigned short* yb   = (unsigned short*)(ws + 64 * MB);   // 16 MB bf16 y
  unsigned short* gb   = (unsigned short*)(ws + 96 * MB);   // 16 MB bf16 swz
  float*          ep   = (float*)(ws + 96 * MB);            // 4 MB (dead before gb)
  unsigned short* w3t  = (unsigned short*)(ws + 112 * MB);  // 6 MB: qwt|kwt|vwt
  unsigned short* owt  = (unsigned short*)(ws + 118 * MB);  // 2 MB
  float*          eb   = (float*)(ws + 120 * MB);           // 64 KB

  prep_kernel<<<BT_ROWS + 4096, 256, 0, stream>>>(
      x, norm_w, norm_b, xn,
      q_w, k_w, v_w, out_w,
      w3t, w3t + (1u << 20), w3t + (2u << 20), owt);

  gemm_qkv8<<<832, 512, 0, stream>>>(xn, w3t, q_b, k_b, v_b, mask, qkv,
                                     emb, emb_w, ep);

  attn_mfma7<<<576, 256, 0, stream>>>(qb, kb, vt, mask, yb, ep, emb_b, eb);

  ln2_kernel<<<BT_ROWS, 256, 0, stream>>>(yb, sb_w, sb_b, eb, gb);

  gemm_out<<<512, 256, 0, stream>>>(gb, owt, out_b, x, out);
}